// Round 7
// baseline (131.901 us; speedup 1.0000x reference)
//
#include <hip/hip_runtime.h>

// Non-local attention, B=1,C=3,H=W=128,k=3 -> L=15876 patches, d=27
#define LQv  15876
#define LP   16384              // padded keys: 1024 tiles of 16
#define LQP  16384              // padded queries
#define HOc  126
#define NCH  16                 // attn split-K chunks (1024 keys each)
// exp2-arg = C2L*(q.k) + ck[key] + (80 - CKS*yy)[query] = 80 - CKS*||q-k||^2
// all folded into MFMA pad dims:
//   q dims 0..26 pre-scaled by C2L; key dim27 = ck*IC2L, query dim27 = C2L
//   key dim29 = 1.0, query dim29 = 80 - CKS*yy   (analytic shift)
// range: arg in [-23, +80] for all queries (overflow @127, flush @-133) - safe
#define C2L  8.243971662222648f
#define IC2L 0.1213006672795172f
#define CKS  4.121985831111324f

typedef __attribute__((ext_vector_type(8))) short bf16x8;
typedef __attribute__((ext_vector_type(4))) float f32x4;

#define MFMA(a,b,c) __builtin_amdgcn_mfma_f32_16x16x32_bf16((a),(b),(c),0,0,0)
#define EXP2(x) __builtin_amdgcn_exp2f(x)

__device__ __forceinline__ unsigned short f2bf_rne(float f) {
    unsigned u = __float_as_uint(f);
    unsigned r = ((u >> 16) & 1u) + 0x7FFFu;
    return (unsigned short)((u + r) >> 16);
}
__device__ __forceinline__ float bf2f(unsigned short h) {
    return __uint_as_float(((unsigned)h) << 16);
}
__device__ __forceinline__ void split_bf(float v, unsigned short& hi, unsigned short& lo) {
    hi = f2bf_rne(v);
    lo = f2bf_rne(v - bf2f(hi));
}
// compile-time patch-dim -> image offset (relative to i*128+j)
__device__ __forceinline__ constexpr int doffc(int d) {
    return (d / 9) * 16384 + ((d % 9) / 3) * 128 + ((d % 9) % 3);
}

// ---------------------------------------------------------------------------
// prep: PAIR-SPLIT over 384 blocks. Lane pair (2m,2m+1) handles one row l:
// half0 = dims 0..15, half1 = dims 16..31 (incl pads). Offsets are
// COMPILE-TIME tables selected by `half` (1 cndmask vs runtime index math).
// ||.||^2 partials combined with one __shfl_xor(ss,1). Roles (128 blk each):
//   role 0: key bf16 hi/lo rows  role 1: query rows (pre-scaled by C2L)
//   role 2: dim-major V, PERMUTED columns (kappa=16t+4g+i -> slot 8g+4t+i)
// ---------------------------------------------------------------------------
__global__ __launch_bounds__(256) void prep_kernel(
    const float* __restrict__ x, const float* __restrict__ y,
    unsigned short* __restrict__ khi, unsigned short* __restrict__ klo,
    unsigned short* __restrict__ qhi, unsigned short* __restrict__ qlo,
    unsigned short* __restrict__ vt)
{
    int gidx = blockIdx.x * 256 + threadIdx.x;   // 384*256 = 98304 threads
    int pair = gidx >> 1, half = gidx & 1;
    int l = pair & (LP - 1);
    int role = pair >> 14;                       // block-uniform (128 blk/role)
    bool real = l < LQv;
    int i = real ? (l / HOc) : 0, j = real ? (l - i * HOc) : 0;
    int base = i * 128 + j;

    if (role < 2) {
        const float* __restrict__ src = role ? y : x;
        float scale = role ? C2L : 1.f;
        __align__(16) unsigned short hh[16], ll[16];
        float ss = 0.f;
#pragma unroll
        for (int it = 0; it < 16; ++it) {
            int offL = doffc(it);
            int offH = (16 + it < 27) ? doffc(16 + it) : 0;
            int off  = half ? offH : offL;
            bool ok  = (it < 11) ? real : (real && !half);
            float v = src[base + off];
            v = ok ? v : 0.f;
            ss = fmaf(v, v, ss);
            split_bf(scale * v, hh[it], ll[it]);
        }
        float tot = ss + __shfl_xor(ss, 1);      // full ||row||^2
        if (half) {                              // pad dims 27..31 = idx 11..15
            if (role == 0) {
                float ckv = real ? (-tot * CKS) : -1e30f;  // pad keys -> p=0
                split_bf(ckv * IC2L, hh[11], ll[11]);
                hh[12] = ll[12] = 0;
                hh[13] = 0x3F80; ll[13] = 0;     // bf16(1.0)
                hh[14] = ll[14] = 0; hh[15] = ll[15] = 0;
            } else {
                split_bf(C2L, hh[11], ll[11]);
                hh[12] = ll[12] = 0;
                split_bf(80.f - CKS * tot, hh[13], ll[13]);  // analytic shift
                hh[14] = ll[14] = 0; hh[15] = ll[15] = 0;
            }
        }
        int d0 = half << 4;
        unsigned short* dh = (role ? qhi : khi) + (size_t)l * 32 + d0;
        unsigned short* dl = (role ? qlo : klo) + (size_t)l * 32 + d0;
        ((uint4*)dh)[0] = ((uint4*)hh)[0]; ((uint4*)dh)[1] = ((uint4*)hh)[1];
        ((uint4*)dl)[0] = ((uint4*)ll)[0]; ((uint4*)dl)[1] = ((uint4*)ll)[1];
    } else {                                     // ---- permuted Vt
        int kap = l & 31;
        int cp = 8 * ((kap >> 2) & 3) + 4 * (kap >> 4) + (kap & 3);
        int lp = (l & ~31) | cp;
        unsigned short* vbase = vt + lp + (half ? 16 * LP : 0);
#pragma unroll
        for (int it = 0; it < 16; ++it) {
            int offL = doffc(it);
            int offH = (16 + it < 27) ? doffc(16 + it) : 0;
            int off  = half ? offH : offL;
            bool ok  = (it < 11) ? real : (real && !half);
            float xv = x[base + off];
            unsigned short v;
            if (it == 11)  // half1 col 27: ones row -> lsum column
                v = ok ? f2bf_rne(xv) : ((real && half) ? (unsigned short)0x3F80
                                                        : (unsigned short)0);
            else
                v = ok ? f2bf_rne(xv) : 0;
            vbase[it * LP] = v;
        }
    }
}

// ---------------------------------------------------------------------------
// attn: register-resident flash attention + LDS 2-phase double-buffer
// staging (R4) + T2 swizzle (R6: bank conflicts 3.1M -> 0).
// R6 POST-MORTEM: MfmaUtil 44 + VALUBusy 45 SUM to ~90 -- pipes serialized,
// not overlapped. Occupancy only 29% (~2.3 blocks/CU resident): not enough
// independent waves per SIMD to fill the MFMA pipe while another wave runs
// exp2. THIS ROUND: 8 blocks/CU. QT=2 (32 q/wave), grid (128,16) = 2048
// blocks, launch_bounds(256,8) caps VGPR at 64 (QT=2 frees 32 regs of
// Q-frag+acc state vs QT=4, so the cap is comfortable -- R1's VGPR=32
// pathology had no LDS staging). MFMA/exp2 totals unchanged; staging
// doubles but is L2-resident; 8 independent barrier phases per CU let
// MFMA and VALU from different blocks co-schedule (m114).
// ---------------------------------------------------------------------------
__device__ __forceinline__ void gload16(const unsigned short* g, unsigned short* l)
{
    // lds dest = wave-uniform base + lane*16B; global src is per-lane
    __builtin_amdgcn_global_load_lds(
        (__attribute__((address_space(1))) void*)g,
        (__attribute__((address_space(3))) void*)l, 16, 0, 0);
}

// swizzled per-lane source offset (u16 units) for row-major K segments:
// row R=lane>>2 keeps its 32-u16 row; 8-u16 chunk C=lane&3 XOR s(R)=(lane>>3)&3
#define SLANE8(lane) ((((lane) & ~3) | (((lane) & 3) ^ (((lane) >> 3) & 3))) * 8)
// chunk-only swizzle for vt (row picked separately)
#define SCHUNK8(lane) ((((lane) & 3) ^ (((lane) >> 3) & 3)) * 8)

__global__ __launch_bounds__(256, 8) void attn_kernel(
    const unsigned short* __restrict__ khi, const unsigned short* __restrict__ klo,
    const unsigned short* __restrict__ qhi, const unsigned short* __restrict__ qlo,
    const unsigned short* __restrict__ vt,  unsigned int* __restrict__ opart)
{
    __shared__ __align__(16) unsigned short lds[2][3072];  // {khi,klo,vt} x 1K u16
    int lane = threadIdx.x & 63;
    int wave = threadIdx.x >> 6;
    int n = lane & 15, g = lane >> 4;
    int gx = g ^ ((n >> 1) & 3);                 // swizzled read chunk
    int qb = blockIdx.x * 128 + wave * 32;       // 32 queries per wave (QT=2)
    int ch = blockIdx.y;

    bf16x8 bqh[2], bql[2];
#pragma unroll
    for (int t = 0; t < 2; ++t) {
        bqh[t] = *(const bf16x8*)(qhi + (size_t)(qb + t * 16 + n) * 32 + g * 8);
        bql[t] = *(const bf16x8*)(qlo + (size_t)(qb + t * 16 + n) * 32 + g * 8);
    }

    f32x4 o0[2], o1[2];
#pragma unroll
    for (int t = 0; t < 2; ++t) {
        o0[t] = (f32x4){0.f, 0.f, 0.f, 0.f};
        o1[t] = (f32x4){0.f, 0.f, 0.f, 0.f};
    }

    int kb0 = ch * 1024;

    // ---- stage tile kb into dst (one buffer): 6 x 1KB segments, split by
    // wave. LDS dest linear (lane*16B); source carries the inverse swizzle.
#define STAGE(dst, kb) do {                                                   \
        if (wave == 0) {                                                      \
            gload16(khi + (size_t)(kb) * 32 + SLANE8(lane),       (dst));     \
            gload16(khi + (size_t)(kb) * 32 + 512 + SLANE8(lane), (dst) + 512);\
        } else if (wave == 1) {                                               \
            gload16(klo + (size_t)(kb) * 32 + SLANE8(lane),       (dst) + 1024);\
            gload16(klo + (size_t)(kb) * 32 + 512 + SLANE8(lane), (dst) + 1536);\
        } else if (wave == 2) {                                               \
            gload16(vt + (size_t)(lane >> 2) * LP + (kb) + SCHUNK8(lane),     \
                    (dst) + 2048);                                            \
        } else {                                                              \
            gload16(vt + (size_t)(16 + (lane >> 2)) * LP + (kb) + SCHUNK8(lane), \
                    (dst) + 2560);                                            \
        }                                                                     \
    } while (0)

    STAGE(lds[0], kb0);
    __syncthreads();

    int buf = 0;
    for (int it = 0; it < 32; ++it) {
        // prefetch next tile into the other buffer (wraps at end; dead write)
        int kbn = kb0 + ((it + 1) & 31) * 32;
        STAGE(lds[buf ^ 1], kbn);

        const unsigned short* L = lds[buf];
        bf16x8 kh0 = *(const bf16x8*)(L + n * 32 + gx * 8);
        bf16x8 kh1 = *(const bf16x8*)(L + (16 + n) * 32 + gx * 8);
        bf16x8 kl0 = *(const bf16x8*)(L + 1024 + n * 32 + gx * 8);
        bf16x8 kl1 = *(const bf16x8*)(L + 1024 + (16 + n) * 32 + gx * 8);
        bf16x8 v0  = *(const bf16x8*)(L + 2048 + n * 32 + gx * 8);
        bf16x8 v1  = *(const bf16x8*)(L + 2048 + (16 + n) * 32 + gx * 8);

#pragma unroll
        for (int qt = 0; qt < 2; ++qt) {
            f32x4 cc0 = {0.f, 0.f, 0.f, 0.f}, cc1 = {0.f, 0.f, 0.f, 0.f};
            cc0 = MFMA(kh0, bqh[qt], cc0); cc1 = MFMA(kh1, bqh[qt], cc1);
            cc0 = MFMA(kh0, bql[qt], cc0); cc1 = MFMA(kh1, bql[qt], cc1);
            cc0 = MFMA(kl0, bqh[qt], cc0); cc1 = MFMA(kl1, bqh[qt], cc1);
            // accumulator IS the exp2 argument (ck, shift, C2L all folded)
            float p0 = EXP2(cc0[0]);
            float p1 = EXP2(cc0[1]);
            float p2 = EXP2(cc0[2]);
            float p3 = EXP2(cc0[3]);
            float p4 = EXP2(cc1[0]);
            float p5 = EXP2(cc1[1]);
            float p6 = EXP2(cc1[2]);
            float p7 = EXP2(cc1[3]);
            // packed p-pairs ARE the PV A-fragment (Vt columns permuted)
            union { unsigned u[4]; bf16x8 v; } ap;
            ap.u[0] = __builtin_amdgcn_perm(__float_as_uint(p1), __float_as_uint(p0), 0x07060302u);
            ap.u[1] = __builtin_amdgcn_perm(__float_as_uint(p3), __float_as_uint(p2), 0x07060302u);
            ap.u[2] = __builtin_amdgcn_perm(__float_as_uint(p5), __float_as_uint(p4), 0x07060302u);
            ap.u[3] = __builtin_amdgcn_perm(__float_as_uint(p7), __float_as_uint(p6), 0x07060302u);
            o0[qt] = MFMA(ap.v, v0, o0[qt]);
            o1[qt] = MFMA(ap.v, v1, o1[qt]);
        }
        __syncthreads();      // emits vmcnt+lgkm drain: buf^1 staged, buf free
        buf ^= 1;
    }
#undef STAGE

    // epilogue: bf16-pack partials; u32 index n holds cols (n, n+16)
#pragma unroll
    for (int qt = 0; qt < 2; ++qt) {
#pragma unroll
        for (int r = 0; r < 4; ++r) {
            unsigned w = ((unsigned)f2bf_rne(o1[qt][r]) << 16) | f2bf_rne(o0[qt][r]);
            size_t row = (size_t)ch * LQP + qb + qt * 16 + 4 * g + r;
            opart[row * 16 + n] = w;
        }
    }
}

// ---------------------------------------------------------------------------
// final: FUSED merge + overlap-add. Block = 8x8 pixel tile x 3 channels
// (grid 16x16). Merges the tile's 10x10 patch rows into LDS (per-(row,pair)
// tasks; proven merge loop + lsum shuffle — 16-lane groups stay row-aligned
// since tasks stride 256), then gathers 9 taps/output from LDS. No atomics,
// no patch buffer. Invalid border rows clamp to l=0 and are never read.
// ---------------------------------------------------------------------------
__global__ __launch_bounds__(256) void final_kernel(
    const unsigned int* __restrict__ opart, float* __restrict__ out)
{
    __shared__ float lpatch[100 * 32];           // 10x10 rows x 32 cols (12.8 KB)
    int tid = threadIdx.x;
    int lane = tid & 63;
    int h0 = (blockIdx.x >> 4) * 8, w0 = (blockIdx.x & 15) * 8;

    for (int t = tid; t < 1600; t += 256) {      // 100 rows x 16 pairs
        int rr = t >> 4, n = t & 15;
        int di = rr / 10, dj = rr - di * 10;
        int I = h0 - 2 + di, J = w0 - 2 + dj;
        bool valid = ((unsigned)I < 126u) && ((unsigned)J < 126u);
        int l = valid ? (I * HOc + J) : 0;       // clamped row never read
        float s0 = 0.f, s1 = 0.f;
#pragma unroll
        for (int c = 0; c < NCH; ++c) {
            unsigned v = opart[((size_t)c * LQP + l) * 16 + n];
            s0 += bf2f((unsigned short)(v & 0xffffu));
            s1 += bf2f((unsigned short)(v >> 16));
        }
        float denom = __shfl(s1, (lane & 48) | 11);  // lsum: pair-11 hi half
        float inv = 1.f / denom;
        lpatch[rr * 32 + n]      = s0 * inv;
        lpatch[rr * 32 + 16 + n] = s1 * inv;
    }
    __syncthreads();

    if (tid < 192) {                             // 3 channels x 64 pixels
        int c = tid >> 6, pix = tid & 63;
        int h = h0 + (pix >> 3), w = w0 + (pix & 7);
        float sum = 0.f; int cnt = 0;
#pragma unroll
        for (int r1 = 0; r1 < 3; ++r1) {
            int I = h - r1; if ((unsigned)I >= 126u) continue;
#pragma unroll
            for (int r2 = 0; r2 < 3; ++r2) {
                int J = w - r2; if ((unsigned)J >= 126u) continue;
                int rr = (I - (h0 - 2)) * 10 + (J - (w0 - 2));
                sum += lpatch[rr * 32 + c * 9 + r1 * 3 + r2];
                ++cnt;
            }
        }
        out[c * 16384 + h * 128 + w] = sum / (float)cnt;
    }
}

// ---------------------------------------------------------------------------
extern "C" void kernel_launch(void* const* d_in, const int* in_sizes, int n_in,
                              void* d_out, int out_size, void* d_ws, size_t ws_size,
                              hipStream_t stream)
{
    const float* x = (const float*)d_in[0];
    const float* y = (const float*)d_in[1];
    float* out = (float*)d_out;

    // ws layout (21 MB)
    unsigned short* khi = (unsigned short*)d_ws;          // LP*32 u16 (1 MB)
    unsigned short* klo = khi + (size_t)LP * 32;          // 1 MB
    unsigned short* qhi = klo + (size_t)LP * 32;          // 1 MB
    unsigned short* qlo = qhi + (size_t)LQP * 32;         // 1 MB
    unsigned short* vt  = qlo + (size_t)LQP * 32;         // 1 MB (dim-major, permuted)
    unsigned int* opart = (unsigned int*)(vt + (size_t)32 * LP); // 16 MB

    dim3 blk(256);
    prep_kernel <<<dim3(384),      blk, 0, stream>>>(x, y, khi, klo, qhi, qlo, vt);
    attn_kernel <<<dim3(128, NCH), blk, 0, stream>>>(khi, klo, qhi, qlo, vt, opart);
    final_kernel<<<dim3(256),      blk, 0, stream>>>(opart, out);
}

// Round 8
// 120.795 us; speedup vs baseline: 1.0919x; 1.0919x over previous
//
#include <hip/hip_runtime.h>

// Non-local attention, B=1,C=3,H=W=128,k=3 -> L=15876 patches, d=27
#define LQv  15876
#define LP   16384              // padded keys: 1024 tiles of 16
#define LQP  16384              // padded queries
#define HOc  126
#define NCH  16                 // attn split-K chunks (1024 keys each)
// exp2-arg = C2L*(q.k) + ck[key] + (80 - CKS*yy)[query] = 80 - CKS*||q-k||^2
// all folded into MFMA pad dims:
//   q dims 0..26 pre-scaled by C2L; key dim27 = ck*IC2L, query dim27 = C2L
//   key dim29 = 1.0, query dim29 = 80 - CKS*yy   (analytic shift)
// range: arg in [-23, +80] for all queries (overflow @127, flush @-133) - safe
#define C2L  8.243971662222648f
#define IC2L 0.1213006672795172f
#define CKS  4.121985831111324f

typedef __attribute__((ext_vector_type(8))) short bf16x8;
typedef __attribute__((ext_vector_type(4))) float f32x4;

#define MFMA(a,b,c) __builtin_amdgcn_mfma_f32_16x16x32_bf16((a),(b),(c),0,0,0)
#define EXP2(x) __builtin_amdgcn_exp2f(x)

__device__ __forceinline__ unsigned short f2bf_rne(float f) {
    unsigned u = __float_as_uint(f);
    unsigned r = ((u >> 16) & 1u) + 0x7FFFu;
    return (unsigned short)((u + r) >> 16);
}
__device__ __forceinline__ float bf2f(unsigned short h) {
    return __uint_as_float(((unsigned)h) << 16);
}
__device__ __forceinline__ void split_bf(float v, unsigned short& hi, unsigned short& lo) {
    hi = f2bf_rne(v);
    lo = f2bf_rne(v - bf2f(hi));
}
// compile-time patch-dim -> image offset (relative to i*128+j)
__device__ __forceinline__ constexpr int doffc(int d) {
    return (d / 9) * 16384 + ((d % 9) / 3) * 128 + ((d % 9) % 3);
}

// ---------------------------------------------------------------------------
// prep: PAIR-SPLIT over 384 blocks. Lane pair (2m,2m+1) handles one row l:
// half0 = dims 0..15, half1 = dims 16..31 (incl pads). Offsets are
// COMPILE-TIME tables selected by `half` (1 cndmask vs runtime index math).
// ||.||^2 partials combined with one __shfl_xor(ss,1). Roles (128 blk each):
//   role 0: key bf16 hi/lo rows  role 1: query rows (pre-scaled by C2L)
//   role 2: dim-major V, PERMUTED columns (kappa=16t+4g+i -> slot 8g+4t+i)
// ---------------------------------------------------------------------------
__global__ __launch_bounds__(256) void prep_kernel(
    const float* __restrict__ x, const float* __restrict__ y,
    unsigned short* __restrict__ khi, unsigned short* __restrict__ klo,
    unsigned short* __restrict__ qhi, unsigned short* __restrict__ qlo,
    unsigned short* __restrict__ vt)
{
    int gidx = blockIdx.x * 256 + threadIdx.x;   // 384*256 = 98304 threads
    int pair = gidx >> 1, half = gidx & 1;
    int l = pair & (LP - 1);
    int role = pair >> 14;                       // block-uniform (128 blk/role)
    bool real = l < LQv;
    int i = real ? (l / HOc) : 0, j = real ? (l - i * HOc) : 0;
    int base = i * 128 + j;

    if (role < 2) {
        const float* __restrict__ src = role ? y : x;
        float scale = role ? C2L : 1.f;
        __align__(16) unsigned short hh[16], ll[16];
        float ss = 0.f;
#pragma unroll
        for (int it = 0; it < 16; ++it) {
            int offL = doffc(it);
            int offH = (16 + it < 27) ? doffc(16 + it) : 0;
            int off  = half ? offH : offL;
            bool ok  = (it < 11) ? real : (real && !half);
            float v = src[base + off];
            v = ok ? v : 0.f;
            ss = fmaf(v, v, ss);
            split_bf(scale * v, hh[it], ll[it]);
        }
        float tot = ss + __shfl_xor(ss, 1);      // full ||row||^2
        if (half) {                              // pad dims 27..31 = idx 11..15
            if (role == 0) {
                float ckv = real ? (-tot * CKS) : -1e30f;  // pad keys -> p=0
                split_bf(ckv * IC2L, hh[11], ll[11]);
                hh[12] = ll[12] = 0;
                hh[13] = 0x3F80; ll[13] = 0;     // bf16(1.0)
                hh[14] = ll[14] = 0; hh[15] = ll[15] = 0;
            } else {
                split_bf(C2L, hh[11], ll[11]);
                hh[12] = ll[12] = 0;
                split_bf(80.f - CKS * tot, hh[13], ll[13]);  // analytic shift
                hh[14] = ll[14] = 0; hh[15] = ll[15] = 0;
            }
        }
        int d0 = half << 4;
        unsigned short* dh = (role ? qhi : khi) + (size_t)l * 32 + d0;
        unsigned short* dl = (role ? qlo : klo) + (size_t)l * 32 + d0;
        ((uint4*)dh)[0] = ((uint4*)hh)[0]; ((uint4*)dh)[1] = ((uint4*)hh)[1];
        ((uint4*)dl)[0] = ((uint4*)ll)[0]; ((uint4*)dl)[1] = ((uint4*)ll)[1];
    } else {                                     // ---- permuted Vt
        int kap = l & 31;
        int cp = 8 * ((kap >> 2) & 3) + 4 * (kap >> 4) + (kap & 3);
        int lp = (l & ~31) | cp;
        unsigned short* vbase = vt + lp + (half ? 16 * LP : 0);
#pragma unroll
        for (int it = 0; it < 16; ++it) {
            int offL = doffc(it);
            int offH = (16 + it < 27) ? doffc(16 + it) : 0;
            int off  = half ? offH : offL;
            bool ok  = (it < 11) ? real : (real && !half);
            float xv = x[base + off];
            unsigned short v;
            if (it == 11)  // half1 col 27: ones row -> lsum column
                v = ok ? f2bf_rne(xv) : ((real && half) ? (unsigned short)0x3F80
                                                        : (unsigned short)0);
            else
                v = ok ? f2bf_rne(xv) : 0;
            vbase[it * LP] = v;
        }
    }
}

// ---------------------------------------------------------------------------
// attn: register-resident flash attention, QT=4 math body (R6-proven) + LDS
// double-buffer staging (R4) + T2 swizzle (R6: conflicts 3.1M -> 0).
// R7 POST-MORTEM: occupancy split refuted AGAIN (57% occ, attn 60->69.5us,
// VGPR squeezed to 32, spill 16MB, staging x2). Occupancy is not the lever.
// R6 arithmetic: per-wave iter ~1125cyc = ~600 MFMA + ~250 VALU/trans +
// ~300-500 STALL around the per-iteration __syncthreads (vmcnt+lgkm drain,
// x32 per wave; compiler may also sink gload_lds issues late).
// THIS ROUND: amortize the drain.
//   - 64-key tiles: 12KB staged/tile (khi 4K + klo 4K + vt 2x2K halves),
//     2 buffers = 24KB LDS. 16 iterations x 1 barrier instead of 32; each
//     drain covered by ~2x compute. vt keeps 32-u16 row pitch per half ->
//     swizzle/bank math identical (khi row 32h+n: quad (4n+gx)%8, h drops).
//   - sched_barrier(0) right after STAGE pins load-issue at region top so
//     the barrier drain finds loads complete.
// Body per 32-key half is bit-identical to R6.
// ---------------------------------------------------------------------------
__device__ __forceinline__ void gload16(const unsigned short* g, unsigned short* l)
{
    // lds dest = wave-uniform base + lane*16B; global src is per-lane
    __builtin_amdgcn_global_load_lds(
        (__attribute__((address_space(1))) void*)g,
        (__attribute__((address_space(3))) void*)l, 16, 0, 0);
}

// swizzled per-lane source offset (u16 units) for row-major K segments:
// row R=lane>>2 keeps its 32-u16 row; 8-u16 chunk C=lane&3 XOR s(R)=(lane>>3)&3
#define SLANE8(lane) ((((lane) & ~3) | (((lane) & 3) ^ (((lane) >> 3) & 3))) * 8)
// chunk-only swizzle for vt (row picked separately)
#define SCHUNK8(lane) ((((lane) & 3) ^ (((lane) >> 3) & 3)) * 8)

__global__ __launch_bounds__(256, 4) void attn_kernel(
    const unsigned short* __restrict__ khi, const unsigned short* __restrict__ klo,
    const unsigned short* __restrict__ qhi, const unsigned short* __restrict__ qlo,
    const unsigned short* __restrict__ vt,  unsigned int* __restrict__ opart)
{
    // 64-key buffer: khi [64][32] @0, klo @2048, vt 2x[32][32] @4096/@5120
    __shared__ __align__(16) unsigned short lds[2][6144];  // 24 KB
    int lane = threadIdx.x & 63;
    int wave = threadIdx.x >> 6;
    int n = lane & 15, g = lane >> 4;
    int gx = g ^ ((n >> 1) & 3);                 // swizzled read chunk
    int qb = blockIdx.x * 256 + wave * 64;
    int ch = blockIdx.y;

    bf16x8 bqh[4], bql[4];
#pragma unroll
    for (int t = 0; t < 4; ++t) {
        bqh[t] = *(const bf16x8*)(qhi + (size_t)(qb + t * 16 + n) * 32 + g * 8);
        bql[t] = *(const bf16x8*)(qlo + (size_t)(qb + t * 16 + n) * 32 + g * 8);
    }

    f32x4 o0[4], o1[4];
#pragma unroll
    for (int t = 0; t < 4; ++t) {
        o0[t] = (f32x4){0.f, 0.f, 0.f, 0.f};
        o1[t] = (f32x4){0.f, 0.f, 0.f, 0.f};
    }

    int kb0 = ch * 1024;

    // ---- stage one 64-key tile (12KB) into dst; 12 x 1KB segments split by
    // wave (w0: khi x4, w1: klo x4, w2: vt half0 x2, w3: vt half1 x2).
    // LDS dest linear (lane*16B); source carries the inverse swizzle.
#define STAGE(dst, kb) do {                                                   \
        if (wave == 0) {                                                      \
            gload16(khi + (size_t)(kb) * 32 +        SLANE8(lane), (dst));    \
            gload16(khi + (size_t)(kb) * 32 +  512 + SLANE8(lane), (dst) + 512);\
            gload16(khi + (size_t)(kb) * 32 + 1024 + SLANE8(lane), (dst) + 1024);\
            gload16(khi + (size_t)(kb) * 32 + 1536 + SLANE8(lane), (dst) + 1536);\
        } else if (wave == 1) {                                               \
            gload16(klo + (size_t)(kb) * 32 +        SLANE8(lane), (dst) + 2048);\
            gload16(klo + (size_t)(kb) * 32 +  512 + SLANE8(lane), (dst) + 2560);\
            gload16(klo + (size_t)(kb) * 32 + 1024 + SLANE8(lane), (dst) + 3072);\
            gload16(klo + (size_t)(kb) * 32 + 1536 + SLANE8(lane), (dst) + 3584);\
        } else if (wave == 2) {                                               \
            gload16(vt + (size_t)(lane >> 2) * LP + (kb) + SCHUNK8(lane),     \
                    (dst) + 4096);                                            \
            gload16(vt + (size_t)(16 + (lane >> 2)) * LP + (kb) + SCHUNK8(lane), \
                    (dst) + 4608);                                            \
        } else {                                                              \
            gload16(vt + (size_t)(lane >> 2) * LP + (kb) + 32 + SCHUNK8(lane),\
                    (dst) + 5120);                                            \
            gload16(vt + (size_t)(16 + (lane >> 2)) * LP + (kb) + 32 + SCHUNK8(lane), \
                    (dst) + 5632);                                            \
        }                                                                     \
    } while (0)

    STAGE(lds[0], kb0);
    __syncthreads();

    int buf = 0;
    for (int it = 0; it < 16; ++it) {            // 16 x 64-key tiles
        // prefetch next tile into the other buffer (wraps at end; dead write)
        int kbn = kb0 + ((it + 1) & 15) * 64;
        STAGE(lds[buf ^ 1], kbn);
        __builtin_amdgcn_sched_barrier(0);       // pin load-issue at region top

        const unsigned short* L = lds[buf];
#pragma unroll
        for (int h = 0; h < 2; ++h) {            // two 32-key halves
            bf16x8 kh0 = *(const bf16x8*)(L + (32 * h + n) * 32 + gx * 8);
            bf16x8 kh1 = *(const bf16x8*)(L + (32 * h + 16 + n) * 32 + gx * 8);
            bf16x8 kl0 = *(const bf16x8*)(L + 2048 + (32 * h + n) * 32 + gx * 8);
            bf16x8 kl1 = *(const bf16x8*)(L + 2048 + (32 * h + 16 + n) * 32 + gx * 8);
            bf16x8 v0  = *(const bf16x8*)(L + 4096 + h * 1024 + n * 32 + gx * 8);
            bf16x8 v1  = *(const bf16x8*)(L + 4096 + h * 1024 + (16 + n) * 32 + gx * 8);

#pragma unroll
            for (int qt = 0; qt < 4; ++qt) {
                f32x4 cc0 = {0.f, 0.f, 0.f, 0.f}, cc1 = {0.f, 0.f, 0.f, 0.f};
                cc0 = MFMA(kh0, bqh[qt], cc0); cc1 = MFMA(kh1, bqh[qt], cc1);
                cc0 = MFMA(kh0, bql[qt], cc0); cc1 = MFMA(kh1, bql[qt], cc1);
                cc0 = MFMA(kl0, bqh[qt], cc0); cc1 = MFMA(kl1, bqh[qt], cc1);
                // accumulator IS the exp2 argument (all consts folded)
                float p0 = EXP2(cc0[0]);
                float p1 = EXP2(cc0[1]);
                float p2 = EXP2(cc0[2]);
                float p3 = EXP2(cc0[3]);
                float p4 = EXP2(cc1[0]);
                float p5 = EXP2(cc1[1]);
                float p6 = EXP2(cc1[2]);
                float p7 = EXP2(cc1[3]);
                // packed p-pairs ARE the PV A-fragment (Vt columns permuted)
                union { unsigned u[4]; bf16x8 v; } ap;
                ap.u[0] = __builtin_amdgcn_perm(__float_as_uint(p1), __float_as_uint(p0), 0x07060302u);
                ap.u[1] = __builtin_amdgcn_perm(__float_as_uint(p3), __float_as_uint(p2), 0x07060302u);
                ap.u[2] = __builtin_amdgcn_perm(__float_as_uint(p5), __float_as_uint(p4), 0x07060302u);
                ap.u[3] = __builtin_amdgcn_perm(__float_as_uint(p7), __float_as_uint(p6), 0x07060302u);
                o0[qt] = MFMA(ap.v, v0, o0[qt]);
                o1[qt] = MFMA(ap.v, v1, o1[qt]);
            }
        }
        __syncthreads();      // one vmcnt+lgkm drain per 64-key tile
        buf ^= 1;
    }
#undef STAGE

    // epilogue: bf16-pack partials; u32 index n holds cols (n, n+16)
#pragma unroll
    for (int qt = 0; qt < 4; ++qt) {
#pragma unroll
        for (int r = 0; r < 4; ++r) {
            unsigned w = ((unsigned)f2bf_rne(o1[qt][r]) << 16) | f2bf_rne(o0[qt][r]);
            size_t row = (size_t)ch * LQP + qb + qt * 16 + 4 * g + r;
            opart[row * 16 + n] = w;
        }
    }
}

// ---------------------------------------------------------------------------
// final: FUSED merge + overlap-add. Block = 8x8 pixel tile x 3 channels
// (grid 16x16). Merges the tile's 10x10 patch rows into LDS (per-(row,pair)
// tasks; proven merge loop + lsum shuffle — 16-lane groups stay row-aligned
// since tasks stride 256), then gathers 9 taps/output from LDS. No atomics,
// no patch buffer. Invalid border rows clamp to l=0 and are never read.
// ---------------------------------------------------------------------------
__global__ __launch_bounds__(256) void final_kernel(
    const unsigned int* __restrict__ opart, float* __restrict__ out)
{
    __shared__ float lpatch[100 * 32];           // 10x10 rows x 32 cols (12.8 KB)
    int tid = threadIdx.x;
    int lane = tid & 63;
    int h0 = (blockIdx.x >> 4) * 8, w0 = (blockIdx.x & 15) * 8;

    for (int t = tid; t < 1600; t += 256) {      // 100 rows x 16 pairs
        int rr = t >> 4, n = t & 15;
        int di = rr / 10, dj = rr - di * 10;
        int I = h0 - 2 + di, J = w0 - 2 + dj;
        bool valid = ((unsigned)I < 126u) && ((unsigned)J < 126u);
        int l = valid ? (I * HOc + J) : 0;       // clamped row never read
        float s0 = 0.f, s1 = 0.f;
#pragma unroll
        for (int c = 0; c < NCH; ++c) {
            unsigned v = opart[((size_t)c * LQP + l) * 16 + n];
            s0 += bf2f((unsigned short)(v & 0xffffu));
            s1 += bf2f((unsigned short)(v >> 16));
        }
        float denom = __shfl(s1, (lane & 48) | 11);  // lsum: pair-11 hi half
        float inv = 1.f / denom;
        lpatch[rr * 32 + n]      = s0 * inv;
        lpatch[rr * 32 + 16 + n] = s1 * inv;
    }
    __syncthreads();

    if (tid < 192) {                             // 3 channels x 64 pixels
        int c = tid >> 6, pix = tid & 63;
        int h = h0 + (pix >> 3), w = w0 + (pix & 7);
        float sum = 0.f; int cnt = 0;
#pragma unroll
        for (int r1 = 0; r1 < 3; ++r1) {
            int I = h - r1; if ((unsigned)I >= 126u) continue;
#pragma unroll
            for (int r2 = 0; r2 < 3; ++r2) {
                int J = w - r2; if ((unsigned)J >= 126u) continue;
                int rr = (I - (h0 - 2)) * 10 + (J - (w0 - 2));
                sum += lpatch[rr * 32 + c * 9 + r1 * 3 + r2];
                ++cnt;
            }
        }
        out[c * 16384 + h * 128 + w] = sum / (float)cnt;
    }
}

// ---------------------------------------------------------------------------
extern "C" void kernel_launch(void* const* d_in, const int* in_sizes, int n_in,
                              void* d_out, int out_size, void* d_ws, size_t ws_size,
                              hipStream_t stream)
{
    const float* x = (const float*)d_in[0];
    const float* y = (const float*)d_in[1];
    float* out = (float*)d_out;

    // ws layout (21 MB)
    unsigned short* khi = (unsigned short*)d_ws;          // LP*32 u16 (1 MB)
    unsigned short* klo = khi + (size_t)LP * 32;          // 1 MB
    unsigned short* qhi = klo + (size_t)LP * 32;          // 1 MB
    unsigned short* qlo = qhi + (size_t)LQP * 32;         // 1 MB
    unsigned short* vt  = qlo + (size_t)LQP * 32;         // 1 MB (dim-major, permuted)
    unsigned int* opart = (unsigned int*)(vt + (size_t)32 * LP); // 16 MB

    dim3 blk(256);
    prep_kernel <<<dim3(384),     blk, 0, stream>>>(x, y, khi, klo, qhi, qlo, vt);
    attn_kernel <<<dim3(64, NCH), blk, 0, stream>>>(khi, klo, qhi, qlo, vt, opart);
    final_kernel<<<dim3(256),     blk, 0, stream>>>(opart, out);
}

// Round 9
// 120.460 us; speedup vs baseline: 1.0950x; 1.0028x over previous
//
#include <hip/hip_runtime.h>

// Non-local attention, B=1,C=3,H=W=128,k=3 -> L=15876 patches, d=27
#define LQv  15876
#define LP   16384              // padded keys: 1024 tiles of 16
#define LQP  16384              // padded queries
#define HOc  126
#define NCH  16                 // attn split-K chunks (1024 keys each)
// exp2-arg = C2L*(q.k) + ck[key] + (80 - CKS*yy)[query] = 80 - CKS*||q-k||^2
// all folded into MFMA pad dims:
//   q dims 0..26 pre-scaled by C2L; key dim27 = ck*IC2L, query dim27 = C2L
//   key dim29 = 1.0, query dim29 = 80 - CKS*yy   (analytic shift)
// range: arg in [-23, +80] for all queries (overflow @127, flush @-133) - safe
#define C2L  8.243971662222648f
#define IC2L 0.1213006672795172f
#define CKS  4.121985831111324f

typedef __attribute__((ext_vector_type(8))) short bf16x8;
typedef __attribute__((ext_vector_type(4))) float f32x4;

#define MFMA(a,b,c) __builtin_amdgcn_mfma_f32_16x16x32_bf16((a),(b),(c),0,0,0)
#define EXP2(x) __builtin_amdgcn_exp2f(x)

__device__ __forceinline__ unsigned short f2bf_rne(float f) {
    unsigned u = __float_as_uint(f);
    unsigned r = ((u >> 16) & 1u) + 0x7FFFu;
    return (unsigned short)((u + r) >> 16);
}
__device__ __forceinline__ float bf2f(unsigned short h) {
    return __uint_as_float(((unsigned)h) << 16);
}
__device__ __forceinline__ void split_bf(float v, unsigned short& hi, unsigned short& lo) {
    hi = f2bf_rne(v);
    lo = f2bf_rne(v - bf2f(hi));
}
// compile-time patch-dim -> image offset (relative to i*128+j)
__device__ __forceinline__ constexpr int doffc(int d) {
    return (d / 9) * 16384 + ((d % 9) / 3) * 128 + ((d % 9) % 3);
}

// ---------------------------------------------------------------------------
// prep: PAIR-SPLIT over 384 blocks. Lane pair (2m,2m+1) handles one row l:
// half0 = dims 0..15, half1 = dims 16..31 (incl pads). Offsets are
// COMPILE-TIME tables selected by `half` (1 cndmask vs runtime index math).
// ||.||^2 partials combined with one __shfl_xor(ss,1). Roles (128 blk each):
//   role 0: key bf16 hi/lo rows  role 1: query rows (pre-scaled by C2L)
//   role 2: dim-major V, PERMUTED columns (kappa=16t+4g+i -> slot 8g+4t+i)
// ---------------------------------------------------------------------------
__global__ __launch_bounds__(256) void prep_kernel(
    const float* __restrict__ x, const float* __restrict__ y,
    unsigned short* __restrict__ khi, unsigned short* __restrict__ klo,
    unsigned short* __restrict__ qhi, unsigned short* __restrict__ qlo,
    unsigned short* __restrict__ vt)
{
    int gidx = blockIdx.x * 256 + threadIdx.x;   // 384*256 = 98304 threads
    int pair = gidx >> 1, half = gidx & 1;
    int l = pair & (LP - 1);
    int role = pair >> 14;                       // block-uniform (128 blk/role)
    bool real = l < LQv;
    int i = real ? (l / HOc) : 0, j = real ? (l - i * HOc) : 0;
    int base = i * 128 + j;

    if (role < 2) {
        const float* __restrict__ src = role ? y : x;
        float scale = role ? C2L : 1.f;
        __align__(16) unsigned short hh[16], ll[16];
        float ss = 0.f;
#pragma unroll
        for (int it = 0; it < 16; ++it) {
            int offL = doffc(it);
            int offH = (16 + it < 27) ? doffc(16 + it) : 0;
            int off  = half ? offH : offL;
            bool ok  = (it < 11) ? real : (real && !half);
            float v = src[base + off];
            v = ok ? v : 0.f;
            ss = fmaf(v, v, ss);
            split_bf(scale * v, hh[it], ll[it]);
        }
        float tot = ss + __shfl_xor(ss, 1);      // full ||row||^2
        if (half) {                              // pad dims 27..31 = idx 11..15
            if (role == 0) {
                float ckv = real ? (-tot * CKS) : -1e30f;  // pad keys -> p=0
                split_bf(ckv * IC2L, hh[11], ll[11]);
                hh[12] = ll[12] = 0;
                hh[13] = 0x3F80; ll[13] = 0;     // bf16(1.0)
                hh[14] = ll[14] = 0; hh[15] = ll[15] = 0;
            } else {
                split_bf(C2L, hh[11], ll[11]);
                hh[12] = ll[12] = 0;
                split_bf(80.f - CKS * tot, hh[13], ll[13]);  // analytic shift
                hh[14] = ll[14] = 0; hh[15] = ll[15] = 0;
            }
        }
        int d0 = half << 4;
        unsigned short* dh = (role ? qhi : khi) + (size_t)l * 32 + d0;
        unsigned short* dl = (role ? qlo : klo) + (size_t)l * 32 + d0;
        ((uint4*)dh)[0] = ((uint4*)hh)[0]; ((uint4*)dh)[1] = ((uint4*)hh)[1];
        ((uint4*)dl)[0] = ((uint4*)ll)[0]; ((uint4*)dl)[1] = ((uint4*)ll)[1];
    } else {                                     // ---- permuted Vt
        int kap = l & 31;
        int cp = 8 * ((kap >> 2) & 3) + 4 * (kap >> 4) + (kap & 3);
        int lp = (l & ~31) | cp;
        unsigned short* vbase = vt + lp + (half ? 16 * LP : 0);
#pragma unroll
        for (int it = 0; it < 16; ++it) {
            int offL = doffc(it);
            int offH = (16 + it < 27) ? doffc(16 + it) : 0;
            int off  = half ? offH : offL;
            bool ok  = (it < 11) ? real : (real && !half);
            float xv = x[base + off];
            unsigned short v;
            if (it == 11)  // half1 col 27: ones row -> lsum column
                v = ok ? f2bf_rne(xv) : ((real && half) ? (unsigned short)0x3F80
                                                        : (unsigned short)0);
            else
                v = ok ? f2bf_rne(xv) : 0;
            vbase[it * LP] = v;
        }
    }
}

// ---------------------------------------------------------------------------
// attn: register-resident flash attention, QT=4 math body + LDS double-buffer
// staging (R4) + T2 swizzle (R6: conflicts 0) + 64-key tiles (R8: 1 barrier
// per 64 keys).
// R8 POST-MORTEM: MfmaUtil 50 + VALUBusy 50 = 100, ZERO overlap. VGPR=64 is
// the tell: compiler targeted the 8-wave boundary (useless -- grid-limited
// at 2.3 waves/SIMD) and 64 regs = Q(32)+acc(32) exactly, so it CANNOT hold
// two (h,qt) iterations' cc/p state -> no cross-iteration pipelining -> the
// wave alternates pipes serially (45% execute, 55% dep-stall).
// THIS ROUND: un-starve the scheduler.
//   - launch_bounds(256,2): VGPR cap 256 (resident 2.3 blocks/CU unaffected
//     up to ~192 VGPR).
//   - hoist all 12 ds_read_b128 (both halves) into named regs right after
//     the barrier (+48 VGPR, compile-time indices) -> LDS latency off the
//     chain; scheduler can interleave the 8 (h,qt) bodies: issue next QK
//     MFMAs (1cyc each, pipe runs background) under current exp2/perm VALU.
// Verification: VGPR 110-190, WRITE_SIZE stays 16.4MB (no spill),
// MfmaUtil+VALUBusy > 100 if overlap materializes.
// ---------------------------------------------------------------------------
__device__ __forceinline__ void gload16(const unsigned short* g, unsigned short* l)
{
    // lds dest = wave-uniform base + lane*16B; global src is per-lane
    __builtin_amdgcn_global_load_lds(
        (__attribute__((address_space(1))) void*)g,
        (__attribute__((address_space(3))) void*)l, 16, 0, 0);
}

// swizzled per-lane source offset (u16 units) for row-major K segments:
// row R=lane>>2 keeps its 32-u16 row; 8-u16 chunk C=lane&3 XOR s(R)=(lane>>3)&3
#define SLANE8(lane) ((((lane) & ~3) | (((lane) & 3) ^ (((lane) >> 3) & 3))) * 8)
// chunk-only swizzle for vt (row picked separately)
#define SCHUNK8(lane) ((((lane) & 3) ^ (((lane) >> 3) & 3)) * 8)

__global__ __launch_bounds__(256, 2) void attn_kernel(
    const unsigned short* __restrict__ khi, const unsigned short* __restrict__ klo,
    const unsigned short* __restrict__ qhi, const unsigned short* __restrict__ qlo,
    const unsigned short* __restrict__ vt,  unsigned int* __restrict__ opart)
{
    // 64-key buffer: khi [64][32] @0, klo @2048, vt 2x[32][32] @4096/@5120
    __shared__ __align__(16) unsigned short lds[2][6144];  // 24 KB
    int lane = threadIdx.x & 63;
    int wave = threadIdx.x >> 6;
    int n = lane & 15, g = lane >> 4;
    int gx = g ^ ((n >> 1) & 3);                 // swizzled read chunk
    int qb = blockIdx.x * 256 + wave * 64;
    int ch = blockIdx.y;

    bf16x8 bqh[4], bql[4];
#pragma unroll
    for (int t = 0; t < 4; ++t) {
        bqh[t] = *(const bf16x8*)(qhi + (size_t)(qb + t * 16 + n) * 32 + g * 8);
        bql[t] = *(const bf16x8*)(qlo + (size_t)(qb + t * 16 + n) * 32 + g * 8);
    }

    f32x4 o0[4], o1[4];
#pragma unroll
    for (int t = 0; t < 4; ++t) {
        o0[t] = (f32x4){0.f, 0.f, 0.f, 0.f};
        o1[t] = (f32x4){0.f, 0.f, 0.f, 0.f};
    }

    int kb0 = ch * 1024;

    // ---- stage one 64-key tile (12KB) into dst; 12 x 1KB segments split by
    // wave (w0: khi x4, w1: klo x4, w2: vt half0 x2, w3: vt half1 x2).
    // LDS dest linear (lane*16B); source carries the inverse swizzle.
#define STAGE(dst, kb) do {                                                   \
        if (wave == 0) {                                                      \
            gload16(khi + (size_t)(kb) * 32 +        SLANE8(lane), (dst));    \
            gload16(khi + (size_t)(kb) * 32 +  512 + SLANE8(lane), (dst) + 512);\
            gload16(khi + (size_t)(kb) * 32 + 1024 + SLANE8(lane), (dst) + 1024);\
            gload16(khi + (size_t)(kb) * 32 + 1536 + SLANE8(lane), (dst) + 1536);\
        } else if (wave == 1) {                                               \
            gload16(klo + (size_t)(kb) * 32 +        SLANE8(lane), (dst) + 2048);\
            gload16(klo + (size_t)(kb) * 32 +  512 + SLANE8(lane), (dst) + 2560);\
            gload16(klo + (size_t)(kb) * 32 + 1024 + SLANE8(lane), (dst) + 3072);\
            gload16(klo + (size_t)(kb) * 32 + 1536 + SLANE8(lane), (dst) + 3584);\
        } else if (wave == 2) {                                               \
            gload16(vt + (size_t)(lane >> 2) * LP + (kb) + SCHUNK8(lane),     \
                    (dst) + 4096);                                            \
            gload16(vt + (size_t)(16 + (lane >> 2)) * LP + (kb) + SCHUNK8(lane), \
                    (dst) + 4608);                                            \
        } else {                                                              \
            gload16(vt + (size_t)(lane >> 2) * LP + (kb) + 32 + SCHUNK8(lane),\
                    (dst) + 5120);                                            \
            gload16(vt + (size_t)(16 + (lane >> 2)) * LP + (kb) + 32 + SCHUNK8(lane), \
                    (dst) + 5632);                                            \
        }                                                                     \
    } while (0)

    STAGE(lds[0], kb0);
    __syncthreads();

    int buf = 0;
    for (int it = 0; it < 16; ++it) {            // 16 x 64-key tiles
        // prefetch next tile into the other buffer (wraps at end; dead write)
        int kbn = kb0 + ((it + 1) & 15) * 64;
        STAGE(lds[buf ^ 1], kbn);
        __builtin_amdgcn_sched_barrier(0);       // pin load-issue at region top

        const unsigned short* L = lds[buf];
        // hoist BOTH halves' K/V reads into registers (compile-time indices)
        bf16x8 kh[2][2], kl[2][2], vv[2][2];
#pragma unroll
        for (int h = 0; h < 2; ++h) {
            kh[h][0] = *(const bf16x8*)(L + (32 * h + n) * 32 + gx * 8);
            kh[h][1] = *(const bf16x8*)(L + (32 * h + 16 + n) * 32 + gx * 8);
            kl[h][0] = *(const bf16x8*)(L + 2048 + (32 * h + n) * 32 + gx * 8);
            kl[h][1] = *(const bf16x8*)(L + 2048 + (32 * h + 16 + n) * 32 + gx * 8);
            vv[h][0] = *(const bf16x8*)(L + 4096 + h * 1024 + n * 32 + gx * 8);
            vv[h][1] = *(const bf16x8*)(L + 4096 + h * 1024 + (16 + n) * 32 + gx * 8);
        }

#pragma unroll
        for (int h = 0; h < 2; ++h) {            // two 32-key halves
#pragma unroll
            for (int qt = 0; qt < 4; ++qt) {
                f32x4 cc0 = {0.f, 0.f, 0.f, 0.f}, cc1 = {0.f, 0.f, 0.f, 0.f};
                cc0 = MFMA(kh[h][0], bqh[qt], cc0); cc1 = MFMA(kh[h][1], bqh[qt], cc1);
                cc0 = MFMA(kh[h][0], bql[qt], cc0); cc1 = MFMA(kh[h][1], bql[qt], cc1);
                cc0 = MFMA(kl[h][0], bqh[qt], cc0); cc1 = MFMA(kl[h][1], bqh[qt], cc1);
                // accumulator IS the exp2 argument (all consts folded)
                float p0 = EXP2(cc0[0]);
                float p1 = EXP2(cc0[1]);
                float p2 = EXP2(cc0[2]);
                float p3 = EXP2(cc0[3]);
                float p4 = EXP2(cc1[0]);
                float p5 = EXP2(cc1[1]);
                float p6 = EXP2(cc1[2]);
                float p7 = EXP2(cc1[3]);
                // packed p-pairs ARE the PV A-fragment (Vt columns permuted)
                union { unsigned u[4]; bf16x8 v; } ap;
                ap.u[0] = __builtin_amdgcn_perm(__float_as_uint(p1), __float_as_uint(p0), 0x07060302u);
                ap.u[1] = __builtin_amdgcn_perm(__float_as_uint(p3), __float_as_uint(p2), 0x07060302u);
                ap.u[2] = __builtin_amdgcn_perm(__float_as_uint(p5), __float_as_uint(p4), 0x07060302u);
                ap.u[3] = __builtin_amdgcn_perm(__float_as_uint(p7), __float_as_uint(p6), 0x07060302u);
                o0[qt] = MFMA(ap.v, vv[h][0], o0[qt]);
                o1[qt] = MFMA(ap.v, vv[h][1], o1[qt]);
            }
        }
        __syncthreads();      // one vmcnt+lgkm drain per 64-key tile
        buf ^= 1;
    }
#undef STAGE

    // epilogue: bf16-pack partials; u32 index n holds cols (n, n+16)
#pragma unroll
    for (int qt = 0; qt < 4; ++qt) {
#pragma unroll
        for (int r = 0; r < 4; ++r) {
            unsigned w = ((unsigned)f2bf_rne(o1[qt][r]) << 16) | f2bf_rne(o0[qt][r]);
            size_t row = (size_t)ch * LQP + qb + qt * 16 + 4 * g + r;
            opart[row * 16 + n] = w;
        }
    }
}

// ---------------------------------------------------------------------------
// final: FUSED merge + overlap-add. Block = 8x8 pixel tile x 3 channels
// (grid 16x16). Merges the tile's 10x10 patch rows into LDS (per-(row,pair)
// tasks; proven merge loop + lsum shuffle — 16-lane groups stay row-aligned
// since tasks stride 256), then gathers 9 taps/output from LDS. No atomics,
// no patch buffer. Invalid border rows clamp to l=0 and are never read.
// ---------------------------------------------------------------------------
__global__ __launch_bounds__(256) void final_kernel(
    const unsigned int* __restrict__ opart, float* __restrict__ out)
{
    __shared__ float lpatch[100 * 32];           // 10x10 rows x 32 cols (12.8 KB)
    int tid = threadIdx.x;
    int lane = tid & 63;
    int h0 = (blockIdx.x >> 4) * 8, w0 = (blockIdx.x & 15) * 8;

    for (int t = tid; t < 1600; t += 256) {      // 100 rows x 16 pairs
        int rr = t >> 4, n = t & 15;
        int di = rr / 10, dj = rr - di * 10;
        int I = h0 - 2 + di, J = w0 - 2 + dj;
        bool valid = ((unsigned)I < 126u) && ((unsigned)J < 126u);
        int l = valid ? (I * HOc + J) : 0;       // clamped row never read
        float s0 = 0.f, s1 = 0.f;
#pragma unroll
        for (int c = 0; c < NCH; ++c) {
            unsigned v = opart[((size_t)c * LQP + l) * 16 + n];
            s0 += bf2f((unsigned short)(v & 0xffffu));
            s1 += bf2f((unsigned short)(v >> 16));
        }
        float denom = __shfl(s1, (lane & 48) | 11);  // lsum: pair-11 hi half
        float inv = 1.f / denom;
        lpatch[rr * 32 + n]      = s0 * inv;
        lpatch[rr * 32 + 16 + n] = s1 * inv;
    }
    __syncthreads();

    if (tid < 192) {                             // 3 channels x 64 pixels
        int c = tid >> 6, pix = tid & 63;
        int h = h0 + (pix >> 3), w = w0 + (pix & 7);
        float sum = 0.f; int cnt = 0;
#pragma unroll
        for (int r1 = 0; r1 < 3; ++r1) {
            int I = h - r1; if ((unsigned)I >= 126u) continue;
#pragma unroll
            for (int r2 = 0; r2 < 3; ++r2) {
                int J = w - r2; if ((unsigned)J >= 126u) continue;
                int rr = (I - (h0 - 2)) * 10 + (J - (w0 - 2));
                sum += lpatch[rr * 32 + c * 9 + r1 * 3 + r2];
                ++cnt;
            }
        }
        out[c * 16384 + h * 128 + w] = sum / (float)cnt;
    }
}

// ---------------------------------------------------------------------------
extern "C" void kernel_launch(void* const* d_in, const int* in_sizes, int n_in,
                              void* d_out, int out_size, void* d_ws, size_t ws_size,
                              hipStream_t stream)
{
    const float* x = (const float*)d_in[0];
    const float* y = (const float*)d_in[1];
    float* out = (float*)d_out;

    // ws layout (21 MB)
    unsigned short* khi = (unsigned short*)d_ws;          // LP*32 u16 (1 MB)
    unsigned short* klo = khi + (size_t)LP * 32;          // 1 MB
    unsigned short* qhi = klo + (size_t)LP * 32;          // 1 MB
    unsigned short* qlo = qhi + (size_t)LQP * 32;         // 1 MB
    unsigned short* vt  = qlo + (size_t)LQP * 32;         // 1 MB (dim-major, permuted)
    unsigned int* opart = (unsigned int*)(vt + (size_t)32 * LP); // 16 MB

    dim3 blk(256);
    prep_kernel <<<dim3(384),     blk, 0, stream>>>(x, y, khi, klo, qhi, qlo, vt);
    attn_kernel <<<dim3(64, NCH), blk, 0, stream>>>(khi, klo, qhi, qlo, vt, opart);
    final_kernel<<<dim3(256),     blk, 0, stream>>>(opart, out);
}